// Round 6
// baseline (784.887 us; speedup 1.0000x reference)
//
#include <hip/hip_runtime.h>
#include <hip/hip_bf16.h>
#include <math.h>

// Problem constants (from reference)
#define N_NODES 10000
#define N_EDGES 80000
#define N_GRAPHS 64
#define NH 4
#define HD 512
#define HDTOT 2048   // NH*HD
#define EMB 768
#define HFEAT 512
#define MAXDEG 512   // LDS softmax-weight capacity per node

typedef _Float16 half8 __attribute__((ext_vector_type(8)));
typedef _Float16 half4 __attribute__((ext_vector_type(4)));
typedef float f32x4 __attribute__((ext_vector_type(4)));

// Async global->LDS, 16B per lane. LDS dest = wave-uniform base + lane*16;
// the GLOBAL SOURCE ADDRESS IS PER-LANE. Lanes fetch their row's K-granules
// in XOR-permuted order, so the DMA lands a swizzled LDS image from a PLAIN
// row-major global plane. Zero VALU repack.
__device__ __forceinline__ void gload_lds16(const void* g, void* l) {
  __builtin_amdgcn_global_load_lds(
      (const __attribute__((address_space(1))) unsigned int*)g,
      (__attribute__((address_space(3))) unsigned int*)l, 16, 0, 0);
}

// Raw barrier WITHOUT the __syncthreads() vmcnt(0) drain.
__device__ __forceinline__ void wgbar() {
  asm volatile("" ::: "memory");
  __builtin_amdgcn_s_barrier();
  asm volatile("" ::: "memory");
}

template <int N>
__device__ __forceinline__ void vmwait() {
  asm volatile("s_waitcnt vmcnt(%0)" ::"n"(N) : "memory");
}

// ---------------------------------------------------------------------------
// Plain-fp16 MFMA GEMM (m97-structure): C = act(A @ B + bias), fp16 planes.
// Proven workhorse (763 TF effective). <128> instance used for N=512 GEMMs
// (R6: hidden chain + Wfc switched from <64> — 2x MFMA per staging load)
// and the M-remainder of the big fc GEMMs. Tile BM x 128, 256 thr, K%64==0.
// ---------------------------------------------------------------------------
template <int BM>
__global__ __launch_bounds__(256) void gemm_f16_kernel(
    const _Float16* __restrict__ A, const _Float16* __restrict__ BT,
    const float* __restrict__ bias, _Float16* __restrict__ C,
    int M, int N, int K, int act) {
  constexpr int WR = (BM == 128) ? 2 : 1;
  constexpr int WC = 4 / WR;
  constexpr int MI = (BM / WR) / 16;
  constexpr int NI = (128 / WC) / 16;
  constexpr int NW = NI * 16;
  constexpr int CS = NW + 4;
  constexpr int GPR = NW / 8;

  __shared__ _Float16 smem[(BM + 128) * 64];
  _Float16* As = smem;
  _Float16* Bs = smem + BM * 64;

  const int bn = blockIdx.x * 128, bm = blockIdx.y * BM;
  const int t = threadIdx.x;
  const int lane = t & 63, wave = t >> 6;
  const int wr = wave / WC, wc = wave % WC;
  const int m0 = wr * (BM / WR), n0 = wc * NW;
  const int fr = lane & 15, fq = lane >> 4;

  f32x4 acc[MI][NI];
#pragma unroll
  for (int i = 0; i < MI; ++i)
#pragma unroll
    for (int j = 0; j < NI; ++j) acc[i][j] = (f32x4){0.f, 0.f, 0.f, 0.f};

  for (int k0 = 0; k0 < K; k0 += 64) {
    __syncthreads();
#pragma unroll
    for (int it = 0; it < BM / 32; ++it) {
      int gid = it * 256 + t;
      int r = gid >> 3;
      int q = (gid & 7) ^ (r & 7);
      int grow = bm + r;
      if (grow >= M) grow = M - 1;
      gload_lds16(A + (size_t)grow * K + k0 + q * 8,
                  &As[(it * 256 + wave * 64) * 8]);
    }
#pragma unroll
    for (int it = 0; it < 4; ++it) {
      int gid = it * 256 + t;
      int r = gid >> 3;
      int q = (gid & 7) ^ (r & 7);
      gload_lds16(BT + (size_t)(bn + r) * K + k0 + q * 8,
                  &Bs[(it * 256 + wave * 64) * 8]);
    }
    __syncthreads();

#pragma unroll
    for (int kk = 0; kk < 2; ++kk) {
      half8 af[MI], bf[NI];
#pragma unroll
      for (int mi = 0; mi < MI; ++mi) {
        int m = m0 + mi * 16 + fr;
        af[mi] = *(const half8*)&As[m * 64 + (((kk * 4 + fq) ^ (m & 7))) * 8];
      }
#pragma unroll
      for (int ni = 0; ni < NI; ++ni) {
        int n = n0 + ni * 16 + fr;
        bf[ni] = *(const half8*)&Bs[n * 64 + (((kk * 4 + fq) ^ (n & 7))) * 8];
      }
#pragma unroll
      for (int mi = 0; mi < MI; ++mi)
#pragma unroll
        for (int ni = 0; ni < NI; ++ni)
          acc[mi][ni] = __builtin_amdgcn_mfma_f32_16x16x32_f16(
              af[mi], bf[ni], acc[mi][ni], 0, 0, 0);
    }
  }
  __syncthreads();
  _Float16* cs = smem + wave * 16 * CS;
#pragma unroll
  for (int mi = 0; mi < MI; ++mi) {
#pragma unroll
    for (int ni = 0; ni < NI; ++ni) {
      float bb = bias ? bias[bn + n0 + ni * 16 + fr] : 0.f;
#pragma unroll
      for (int j = 0; j < 4; ++j) {
        float v = acc[mi][ni][j] + bb;
        if (act == 1) v = v > 0.f ? v : expm1f(v);
        cs[(fq * 4 + j) * CS + ni * 16 + fr] = (_Float16)v;
      }
    }
#pragma unroll
    for (int i = 0; i < NW / 32; ++i) {
      int piece = i * 64 + lane;
      int r = piece / GPR, g = piece % GPR;
      int grow = bm + m0 + mi * 16 + r;
      if (grow < M) {
        half8 v = *(const half8*)&cs[r * CS + g * 8];
        *(half8*)&C[(size_t)grow * N + bn + n0 + g * 8] = v;
      }
    }
  }
}

// ---------------------------------------------------------------------------
// 256x256 FINE-PHASED pipelined GEMM. R5 measured 852 TF / MfmaUtil 36.6%
// (beats m97's 763). R6: upgraded each phase from one barrier to the m201
// two-barrier form: {ds_read + stage-issue -> BARRIER -> lgkmcnt(0) ->
// setprio(1) MFMA x16 setprio(0) -> [vmwait] -> BARRIER}. The isolated MFMA
// cluster between barriers creates the wave role-split (T5 prerequisite):
// waves in MFMA co-schedule against waves issuing next phase's LDS/VMEM.
// Barriers were only ADDED vs R5, so R5's verified ledger still holds:
//
// Outstanding-load ledger (2 loads per STAGE_HALF, per thread):
//  prologue: issue {tA0,tB0,tA1,tB1} of t=0 (8); vmwait<4> -> A0,B0 landed.
//  iter t: p0 stages (t+1)A0; p1 stages (t+1)B0 then vmwait<4> -> leaves
//  newest 4 = {(t+1)A0,(t+1)B0} => tA1,tB1 LANDED before p2 reads.
//  p2 stages (t+1)A1; p3 stages (t+1)B1 then vmwait<4> -> leaves
//  {(t+1)A1,(t+1)B1} => (t+1)A0,(t+1)B0 landed before next iter's p0.
//  Tail: last tile stages nothing; its p1 uses vmwait<0> to retire tA1,tB1.
// Slot reuse: stage of (t+1) slot S is >=1 barrier after t-1's last read of S.
//
// Swizzle/frag addressing identical to the twice-verified R1/R5 kernels
// (bank-conflict counter 0). Requires K%64==0, N%256==0, grid%8==0;
// launched with grid=256 (exactly 1 block/CU, 128 KiB LDS, zero tail).
// ---------------------------------------------------------------------------
#define GP_SLOT 8192  // fp16 elems per half-slot (256 rows x 32)

__global__ __launch_bounds__(512, 1) void gemm256p_f16_kernel(
    const _Float16* __restrict__ A, const _Float16* __restrict__ BT,
    const float* __restrict__ bias, _Float16* __restrict__ C,
    int M, int N, int K, int act, int nbx) {
  __shared__ _Float16 smem[8 * GP_SLOT];  // 128 KiB

  int flat = blockIdx.x;
  int nwg = gridDim.x;
  if ((nwg & 7) == 0) flat = (flat & 7) * (nwg >> 3) + (flat >> 3);
  const int bn = (flat % nbx) * 256;
  const int bm = (flat / nbx) * 256;

  const int t = threadIdx.x;
  const int lane = t & 63, wave = t >> 6;
  const int wr = wave >> 2, wc = wave & 3;
  const int m0 = wr * 128, n0 = wc * 64;
  const int fr = lane & 15, fq = lane >> 4;

  // staging source pointers: gi = it*512+t, row r=gi>>2, pos p=gi&3,
  // source granule g = p ^ ((r>>1)&3) (involution).
  const _Float16* sA[2];
  const _Float16* sB[2];
#pragma unroll
  for (int it = 0; it < 2; ++it) {
    int gi = it * 512 + t;
    int r = gi >> 2;
    int g = (gi & 3) ^ ((r >> 1) & 3);
    int ra = bm + r;
    if (ra >= M) ra = M - 1;  // unused when M%256==0 (split host-side)
    sA[it] = A + (size_t)ra * K + g * 8;
    sB[it] = BT + (size_t)(bn + r) * K + g * 8;
  }
  const int ldsbase = (wave * 64) * 8;  // wave-uniform dest elem offset

  // frag offsets within a half-slot (row-major 256x32, granule-swizzled)
  int offA[8], offB[4];
#pragma unroll
  for (int mi = 0; mi < 8; ++mi) {
    int m = m0 + mi * 16 + fr;
    offA[mi] = m * 32 + ((fq ^ ((m >> 1) & 3)) << 3);
  }
#pragma unroll
  for (int ni = 0; ni < 4; ++ni) {
    int n = n0 + ni * 16 + fr;
    offB[ni] = n * 32 + ((fq ^ ((n >> 1) & 3)) << 3);
  }

  f32x4 acc[8][4];
#pragma unroll
  for (int i = 0; i < 8; ++i)
#pragma unroll
    for (int j = 0; j < 4; ++j) acc[i][j] = (f32x4){0.f, 0.f, 0.f, 0.f};

// which: 0=A-k0 1=B-k0 2=A-k1 3=B-k1
#define STAGE_HALF(kt, wh)                                                  \
  do {                                                                      \
    _Float16* dst_ = smem + ((((kt)&1) * 4 + (wh)) * GP_SLOT);              \
    const _Float16* s0_ = ((wh)&1) ? sB[0] : sA[0];                         \
    const _Float16* s1_ = ((wh)&1) ? sB[1] : sA[1];                         \
    size_t ko_ = (size_t)(kt)*64 + (((wh) >> 1) * 32);                      \
    gload_lds16(s0_ + ko_, &dst_[ldsbase]);                                 \
    gload_lds16(s1_ + ko_, &dst_[4096 + ldsbase]);                          \
  } while (0)

// Two-barrier phase (m201 form). MB literal 0/4 (compile-time acc indices).
// STAGE_STMT issues next-tile loads; VM_STMT is the counted vmcnt checkpoint.
#define PHASE(APTR, BPTR, MB, STAGE_STMT, VM_STMT)                          \
  do {                                                                      \
    half8 af_[4], bf_[4];                                                   \
    _Pragma("unroll") for (int i_ = 0; i_ < 4; ++i_)                        \
        af_[i_] = *(const half8*)&(APTR)[offA[(MB) + i_]];                  \
    _Pragma("unroll") for (int n_ = 0; n_ < 4; ++n_)                        \
        bf_[n_] = *(const half8*)&(BPTR)[offB[n_]];                         \
    STAGE_STMT;                                                             \
    wgbar();                                                                \
    asm volatile("s_waitcnt lgkmcnt(0)" ::: "memory");                      \
    __builtin_amdgcn_sched_barrier(0);                                      \
    __builtin_amdgcn_s_setprio(1);                                          \
    _Pragma("unroll") for (int i_ = 0; i_ < 4; ++i_)                        \
        _Pragma("unroll") for (int n_ = 0; n_ < 4; ++n_)                    \
            acc[(MB) + i_][n_] = __builtin_amdgcn_mfma_f32_16x16x32_f16(    \
                af_[i_], bf_[n_], acc[(MB) + i_][n_], 0, 0, 0);             \
    __builtin_amdgcn_s_setprio(0);                                          \
    VM_STMT;                                                                \
    wgbar();                                                                \
  } while (0)

  const int NT = K >> 6;  // K-tiles of 64

  // prologue: stage tile 0 fully; A0,B0 landed before first reads
  STAGE_HALF(0, 0);
  STAGE_HALF(0, 1);
  STAGE_HALF(0, 2);
  STAGE_HALF(0, 3);
  vmwait<4>();
  wgbar();

  for (int tt = 0; tt < NT; ++tt) {
    const bool more = (tt + 1 < NT);
    const _Float16* base = smem + (tt & 1) * 4 * GP_SLOT;
    const _Float16* A0 = base;
    const _Float16* B0 = base + GP_SLOT;
    const _Float16* A1 = base + 2 * GP_SLOT;
    const _Float16* B1 = base + 3 * GP_SLOT;

    // p0: k0, mi 0-3
    PHASE(A0, B0, 0, if (more) STAGE_HALF(tt + 1, 0), (void)0);
    // p1: k0, mi 4-7 ; checkpoint: tA1,tB1 landed (tail: drain)
    PHASE(A0, B0, 4, if (more) STAGE_HALF(tt + 1, 1),
          if (more) vmwait<4>(); else vmwait<0>());
    // p2: k1, mi 0-3
    PHASE(A1, B1, 0, if (more) STAGE_HALF(tt + 1, 2), (void)0);
    // p3: k1, mi 4-7 ; checkpoint: (t+1)A0,(t+1)B0 landed for next p0
    PHASE(A1, B1, 4, if (more) STAGE_HALF(tt + 1, 3),
          if (more) vmwait<4>());
  }
#undef STAGE_HALF
#undef PHASE

  // ---- epilogue: bias+act, per-wave LDS bounce, 16B coalesced stores ----
  constexpr int CS = 68;
  _Float16* cs = smem + wave * 16 * CS;
#pragma unroll
  for (int mi = 0; mi < 8; ++mi) {
#pragma unroll
    for (int ni = 0; ni < 4; ++ni) {
      float bb = bias ? bias[bn + n0 + ni * 16 + fr] : 0.f;
#pragma unroll
      for (int j = 0; j < 4; ++j) {
        float v = acc[mi][ni][j] + bb;
        if (act == 1) v = v > 0.f ? v : expm1f(v);
        cs[(fq * 4 + j) * CS + ni * 16 + fr] = (_Float16)v;
      }
    }
#pragma unroll
    for (int i = 0; i < 2; ++i) {
      int piece = i * 64 + lane;
      int r = piece >> 3, g = piece & 7;
      int grow = bm + m0 + mi * 16 + r;
      if (grow < M) {
        half8 v = *(const half8*)&cs[r * CS + g * 8];
        *(half8*)&C[(size_t)grow * N + bn + n0 + g * 8] = v;
      }
    }
  }
}

// ---------------------------------------------------------------------------
// Transpose + convert weights: W (KxN fp32) -> WT (NxK fp16), PLAIN layout.
// ---------------------------------------------------------------------------
__global__ __launch_bounds__(256) void convert_wt_kernel(
    const float* __restrict__ W, _Float16* __restrict__ WT, int K, int N) {
  __shared__ float tile[32][33];
  W += (size_t)blockIdx.z * K * N;
  WT += (size_t)blockIdx.z * K * N;
  int k0 = blockIdx.x * 32, n0 = blockIdx.y * 32;
  int t = threadIdx.x;
  int r = t >> 3, c4 = (t & 7) * 4;
  float4 v = *(const float4*)(W + (size_t)(k0 + r) * N + n0 + c4);
  tile[r][c4 + 0] = v.x;
  tile[r][c4 + 1] = v.y;
  tile[r][c4 + 2] = v.z;
  tile[r][c4 + 3] = v.w;
  __syncthreads();
  float x0 = tile[c4 + 0][r], x1 = tile[c4 + 1][r];
  float x2 = tile[c4 + 2][r], x3 = tile[c4 + 3][r];
  size_t o = (size_t)(n0 + r) * K + k0 + c4;
  *(half4*)&WT[o] = (half4){(_Float16)x0, (_Float16)x1, (_Float16)x2, (_Float16)x3};
}

// fp32 -> fp16 plane (for the external node_feat input)
__global__ void convert_f32_f16_kernel(const float* __restrict__ x,
                                       _Float16* __restrict__ y, int n4) {
  int gid = blockIdx.x * blockDim.x + threadIdx.x;
  if (gid >= n4) return;
  float4 v = *(const float4*)(x + gid * 4);
  *(half4*)(y + gid * 4) =
      (half4){(_Float16)v.x, (_Float16)v.y, (_Float16)v.z, (_Float16)v.w};
}

// ---------------------------------------------------------------------------
// CSR build (by dst): histogram -> single-block scan -> scatter.
// ---------------------------------------------------------------------------
__global__ void hist_kernel(const int* __restrict__ dst, int* __restrict__ cnt, int E) {
  int gid = blockIdx.x * blockDim.x + threadIdx.x;
  if (gid < E) atomicAdd(&cnt[dst[gid]], 1);
}

__global__ void scan_kernel(const int* __restrict__ cnt, int* __restrict__ row_ptr,
                            int* __restrict__ cursor, int n) {
  __shared__ int part[256];
  int t = threadIdx.x;
  int chunk = (n + 255) / 256;
  int s0 = t * chunk;
  int s1 = min(s0 + chunk, n);
  int sum = 0;
  for (int i = s0; i < s1; ++i) sum += cnt[i];
  part[t] = sum;
  __syncthreads();
  if (t == 0) {
    int acc = 0;
    for (int i = 0; i < 256; ++i) { int v = part[i]; part[i] = acc; acc += v; }
    row_ptr[n] = acc;
  }
  __syncthreads();
  int run = part[t];
  for (int i = s0; i < s1; ++i) {
    row_ptr[i] = run;
    cursor[i] = run;
    run += cnt[i];
  }
}

__global__ void scatter_kernel(const int* __restrict__ src, const int* __restrict__ dst,
                               int* __restrict__ cursor, int* __restrict__ csr_src,
                               int E) {
  int gid = blockIdx.x * blockDim.x + threadIdx.x;
  if (gid < E) {
    int d = dst[gid];
    int pos = atomicAdd(&cursor[d], 1);
    csr_src[pos] = src[gid];
  }
}

// ---------------------------------------------------------------------------
// GAT pieces (feat fp16 plane; edges in CSR order)
// ---------------------------------------------------------------------------
__global__ __launch_bounds__(256) void el_er_kernel(
    const _Float16* __restrict__ feat, const float* __restrict__ al,
    const float* __restrict__ ar, float* __restrict__ el, float* __restrict__ er) {
  int n = blockIdx.x;
  int t = threadIdx.x;
  int h = t >> 6, lane = t & 63;
  half8 f = *(const half8*)(feat + (size_t)n * HDTOT + h * HD + lane * 8);
  const float* ap = al + h * HD + lane * 8;
  const float* rp = ar + h * HD + lane * 8;
  float4 a0 = *(const float4*)ap, a1 = *(const float4*)(ap + 4);
  float4 r0 = *(const float4*)rp, r1 = *(const float4*)(rp + 4);
  float f0 = (float)f[0], f1 = (float)f[1], f2 = (float)f[2], f3 = (float)f[3];
  float f4 = (float)f[4], f5 = (float)f[5], f6 = (float)f[6], f7 = (float)f[7];
  float sl = f0 * a0.x + f1 * a0.y + f2 * a0.z + f3 * a0.w +
             f4 * a1.x + f5 * a1.y + f6 * a1.z + f7 * a1.w;
  float sr = f0 * r0.x + f1 * r0.y + f2 * r0.z + f3 * r0.w +
             f4 * r1.x + f5 * r1.y + f6 * r1.z + f7 * r1.w;
  for (int off = 32; off; off >>= 1) {
    sl += __shfl_down(sl, off);
    sr += __shfl_down(sr, off);
  }
  if (lane == 0) {
    el[n * NH + h] = sl;
    er[n * NH + h] = sr;
  }
}

// ---------------------------------------------------------------------------
// FUSED per-node edge-softmax + aggregate.
// ---------------------------------------------------------------------------
__global__ __launch_bounds__(256) void softmax_aggregate_kernel(
    const _Float16* __restrict__ feat, const float* __restrict__ el,
    const float* __restrict__ er, const int* __restrict__ row_ptr,
    const int* __restrict__ csr_src, float* __restrict__ e_buf,
    const float* __restrict__ bias, _Float16* __restrict__ out) {
  __shared__ float wl[NH][MAXDEG];
  int n = blockIdx.x;
  int t = threadIdx.x;
  int h = t >> 6, lane = t & 63;
  int s = row_ptr[n], epos = row_ptr[n + 1];
  int deg = epos - s;
  bool lds_w = (deg <= MAXDEG);

  if (deg > 0) {
    float ern = er[n * NH + h];
    if (deg <= 64) {
      int p = s + lane;
      bool on = lane < deg;
      float logit = 0.f;
      float m = -INFINITY;
      if (on) {
        float v = el[csr_src[p] * NH + h] + ern;
        logit = v >= 0.f ? v : 0.2f * v;
        m = logit;
      }
#pragma unroll
      for (int off = 32; off; off >>= 1) m = fmaxf(m, __shfl_xor(m, off));
      float ex = on ? expf(logit - m) : 0.f;
      float sum = ex;
#pragma unroll
      for (int off = 32; off; off >>= 1) sum += __shfl_xor(sum, off);
      float inv = 1.f / sum;
      if (on) wl[h][lane] = ex * inv;
    } else if (lds_w) {
      float m = -INFINITY;
      for (int p = s + lane; p < epos; p += 64) {
        float v = el[csr_src[p] * NH + h] + ern;
        v = v >= 0.f ? v : 0.2f * v;
        wl[h][p - s] = v;
        m = fmaxf(m, v);
      }
      for (int off = 32; off; off >>= 1) m = fmaxf(m, __shfl_xor(m, off));
      float sum = 0.f;
      for (int p = s + lane; p < epos; p += 64) {
        float ex = expf(wl[h][p - s] - m);
        wl[h][p - s] = ex;
        sum += ex;
      }
      for (int off = 32; off; off >>= 1) sum += __shfl_xor(sum, off);
      float inv = 1.f / sum;
      for (int p = s + lane; p < epos; p += 64) wl[h][p - s] *= inv;
    } else {
      float m = -INFINITY;
      for (int p = s + lane; p < epos; p += 64) {
        float v = el[csr_src[p] * NH + h] + ern;
        v = v >= 0.f ? v : 0.2f * v;
        e_buf[p * NH + h] = v;
        m = fmaxf(m, v);
      }
      for (int off = 32; off; off >>= 1) m = fmaxf(m, __shfl_xor(m, off));
      float sum = 0.f;
      for (int p = s + lane; p < epos; p += 64) {
        float ex = expf(e_buf[p * NH + h] - m);
        e_buf[p * NH + h] = ex;
        sum += ex;
      }
      for (int off = 32; off; off >>= 1) sum += __shfl_xor(sum, off);
      float inv = 1.f / sum;
      for (int p = s + lane; p < epos; p += 64) e_buf[p * NH + h] *= inv;
    }
  }
  __syncthreads();

  int base = t * 8;
  float acc[8] = {0.f, 0.f, 0.f, 0.f, 0.f, 0.f, 0.f, 0.f};
  int p = s;
  for (; p + 4 <= epos; p += 4) {
    int q = p - s;
    int sn0 = csr_src[p + 0], sn1 = csr_src[p + 1];
    int sn2 = csr_src[p + 2], sn3 = csr_src[p + 3];
    float a0 = lds_w ? wl[h][q + 0] : e_buf[(p + 0) * NH + h];
    float a1 = lds_w ? wl[h][q + 1] : e_buf[(p + 1) * NH + h];
    float a2 = lds_w ? wl[h][q + 2] : e_buf[(p + 2) * NH + h];
    float a3 = lds_w ? wl[h][q + 3] : e_buf[(p + 3) * NH + h];
    half8 f0 = *(const half8*)(feat + (size_t)sn0 * HDTOT + base);
    half8 f1 = *(const half8*)(feat + (size_t)sn1 * HDTOT + base);
    half8 f2 = *(const half8*)(feat + (size_t)sn2 * HDTOT + base);
    half8 f3 = *(const half8*)(feat + (size_t)sn3 * HDTOT + base);
#pragma unroll
    for (int i = 0; i < 8; ++i)
      acc[i] += a0 * (float)f0[i] + a1 * (float)f1[i] +
                a2 * (float)f2[i] + a3 * (float)f3[i];
  }
  for (; p < epos; ++p) {
    int sn = csr_src[p];
    float a = lds_w ? wl[h][p - s] : e_buf[p * NH + h];
    half8 f = *(const half8*)(feat + (size_t)sn * HDTOT + base);
#pragma unroll
    for (int i = 0; i < 8; ++i) acc[i] += a * (float)f[i];
  }
  float4 b0 = *(const float4*)(bias + base);
  float4 b1 = *(const float4*)(bias + base + 4);
  half8 o;
  o[0] = (_Float16)(acc[0] + b0.x); o[1] = (_Float16)(acc[1] + b0.y);
  o[2] = (_Float16)(acc[2] + b0.z); o[3] = (_Float16)(acc[3] + b0.w);
  o[4] = (_Float16)(acc[4] + b1.x); o[5] = (_Float16)(acc[5] + b1.y);
  o[6] = (_Float16)(acc[6] + b1.z); o[7] = (_Float16)(acc[7] + b1.w);
  *(half8*)(out + (size_t)n * HDTOT + base) = o;
}

// ---------------------------------------------------------------------------
// FUSED pool + BN + Whfc matvec + classifier. One block per graph.
// ---------------------------------------------------------------------------
__global__ __launch_bounds__(512) void pool_final_kernel(
    const _Float16* __restrict__ hfeat, const int* __restrict__ graph_id,
    const float* __restrict__ gamma, const float* __restrict__ beta,
    const float* __restrict__ Whfc, const float* __restrict__ bhfc,
    const float* __restrict__ Wf, const float* __restrict__ bf,
    float* __restrict__ out) {
  __shared__ float sh[HFEAT];
  __shared__ float st[HFEAT];
  __shared__ float r0[8], r1[8];
  __shared__ int s_lo, s_hi;
  int g = blockIdx.x, t = threadIdx.x;
  if (t == 0) {
    int lo = 0, hi = N_NODES;
    while (lo < hi) { int m = (lo + hi) >> 1; if (graph_id[m] < g) lo = m + 1; else hi = m; }
    s_lo = lo;
    int lo2 = lo, hi2 = N_NODES;
    while (lo2 < hi2) { int m = (lo2 + hi2) >> 1; if (graph_id[m] < g + 1) lo2 = m + 1; else hi2 = m; }
    s_hi = lo2;
  }
  __syncthreads();
  int lo = s_lo, hi = s_hi;
  int col = t;
  float acc = 0.f;
  for (int n = lo; n < hi; ++n) acc += (float)hfeat[(size_t)n * HFEAT + col];
  float invc = 1.f / fmaxf((float)(hi - lo), 1.f);
  float bnscale = rsqrtf(1.f + 1e-5f);
  sh[col] = acc * invc * bnscale * gamma[col] + beta[col];
  __syncthreads();
  float a2 = bhfc[col];
  for (int k = 0; k < HFEAT; ++k) a2 += sh[k] * Whfc[k * HFEAT + col];
  st[col] = a2 > 0.f ? a2 : expm1f(a2);
  __syncthreads();
  float p0 = st[col] * Wf[col * 2 + 0];
  float p1 = st[col] * Wf[col * 2 + 1];
  for (int off = 32; off; off >>= 1) {
    p0 += __shfl_down(p0, off);
    p1 += __shfl_down(p1, off);
  }
  int w = t >> 6;
  if ((t & 63) == 0) { r0[w] = p0; r1[w] = p1; }
  __syncthreads();
  if (t == 0) {
    float q0 = bf[0], q1 = bf[1];
#pragma unroll
    for (int i = 0; i < 8; ++i) { q0 += r0[i]; q1 += r1[i]; }
    out[g * 2 + 0] = q0;
    out[g * 2 + 1] = q1;
  }
}

// ---------------------------------------------------------------------------
// Host-side launch
// ---------------------------------------------------------------------------
static void gemm_raw(const _Float16* A, const _Float16* wt, const float* bias,
                     _Float16* C, int M, int N, int K, int act,
                     bool small_m_tile, hipStream_t stream) {
  if (small_m_tile) {
    dim3 grid(N / 128, (M + 63) / 64);
    hipLaunchKernelGGL(gemm_f16_kernel<64>, grid, dim3(256), 0, stream,
                       A, wt, bias, C, M, N, K, act);
  } else {
    dim3 grid(N / 128, (M + 127) / 128);
    hipLaunchKernelGGL(gemm_f16_kernel<128>, grid, dim3(256), 0, stream,
                       A, wt, bias, C, M, N, K, act);
  }
}

static void gemm(const _Float16* A, const float* W, _Float16* wt,
                 const float* bias, _Float16* C, int M, int N, int K, int act,
                 bool small_m_tile, hipStream_t stream) {
  hipLaunchKernelGGL(convert_wt_kernel, dim3(K / 32, N / 32, 1), dim3(256),
                     0, stream, W, wt, K, N);
  gemm_raw(A, wt, bias, C, M, N, K, act, small_m_tile, stream);
}

// Big fc GEMM (N=2048): fine-phased 256^2 kernel on rows 0-8191 (grid = 8x32
// = 256 blocks = exactly 1/CU, zero tail), proven <128> kernel on remainder.
static void gemm_big(const _Float16* A, const float* W, _Float16* wt,
                     const float* bias, _Float16* C, int M, int N, int K,
                     int act, hipStream_t stream) {
  hipLaunchKernelGGL(convert_wt_kernel, dim3(K / 32, N / 32, 1), dim3(256),
                     0, stream, W, wt, K, N);
  if (N == 2048 && M > 8192 && (K & 63) == 0) {
    int nbx = N / 256;  // 8
    hipLaunchKernelGGL(gemm256p_f16_kernel, dim3(256), dim3(512), 0, stream,
                       A, wt, bias, C, 8192, N, K, act, nbx);
    int rem = M - 8192;
    dim3 grid(N / 128, (rem + 127) / 128);
    hipLaunchKernelGGL(gemm_f16_kernel<128>, grid, dim3(256), 0, stream,
                       A + (size_t)8192 * K, wt, bias,
                       C + (size_t)8192 * N, rem, N, K, act);
  } else {
    gemm_raw(A, wt, bias, C, M, N, K, act, false, stream);
  }
}

static void gat_layer(const _Float16* h_in, int K_in, const float* W, _Float16* wt,
                      const float* al, const float* ar, const float* b,
                      const int* row_ptr, const int* csr_src,
                      _Float16* featbuf, float* el, float* er,
                      float* e_buf, _Float16* out, hipStream_t stream) {
  gemm_big(h_in, W, wt, nullptr, featbuf, N_NODES, HDTOT, K_in, 0, stream);
  hipLaunchKernelGGL(el_er_kernel, dim3(N_NODES), dim3(256), 0, stream, featbuf, al, ar, el, er);
  hipLaunchKernelGGL(softmax_aggregate_kernel, dim3(N_NODES), dim3(256), 0, stream,
                     featbuf, el, er, row_ptr, csr_src, e_buf, b, out);
}

extern "C" void kernel_launch(void* const* d_in, const int* in_sizes, int n_in,
                              void* d_out, int out_size, void* d_ws, size_t ws_size,
                              hipStream_t stream) {
  const float* node_feat = (const float*)d_in[0];
  const float* W1 = (const float*)d_in[2];
  const float* al1 = (const float*)d_in[3];
  const float* ar1 = (const float*)d_in[4];
  const float* b1 = (const float*)d_in[5];
  const float* W2 = (const float*)d_in[6];
  const float* al2 = (const float*)d_in[7];
  const float* ar2 = (const float*)d_in[8];
  const float* b2 = (const float*)d_in[9];
  const float* Wfc = (const float*)d_in[10];
  const float* bfc = (const float*)d_in[11];
  const float* Wh = (const float*)d_in[14];
  const float* bh = (const float*)d_in[15];
  const float* gamma = (const float*)d_in[16];
  const float* beta = (const float*)d_in[17];
  const float* Whfc = (const float*)d_in[18];
  const float* bhfc = (const float*)d_in[19];
  const float* Wf = (const float*)d_in[20];
  const float* bf = (const float*)d_in[21];
  const int* src = (const int*)d_in[22];
  const int* dst = (const int*)d_in[23];
  const int* graph_id = (const int*)d_in[24];
  float* out = (float*)d_out;

  // Workspace carve-up
  _Float16* P0 = (_Float16*)d_ws;                 // 10000*2048 fp16
  _Float16* P1 = P0 + (size_t)N_NODES * HDTOT;    // 10000*2048 fp16
  _Float16* Pin = P1 + (size_t)N_NODES * HDTOT;   // 10000*768 fp16
  _Float16* wt = Pin + (size_t)N_NODES * EMB;     // 2048*2048 fp16 (shared)
  _Float16* whh = wt + (size_t)2048 * 2048;       // 8*512*512 fp16 (hidden)
  float* el = (float*)(whh + (size_t)8 * HFEAT * HFEAT);
  float* er = el + N_NODES * NH;
  float* e_buf = er + N_NODES * NH;       // N_EDGES*NH (fallback scratch)
  int* cnt = (int*)(e_buf + (size_t)N_EDGES * NH);
  int* row_ptr = cnt + N_NODES;           // N_NODES+1
  int* cursor = row_ptr + N_NODES + 1;
  int* csr_src = cursor + N_NODES;        // N_EDGES

  // --- CSR build (by dst), once per launch ---
  hipMemsetAsync(cnt, 0, N_NODES * sizeof(int), stream);
  hipLaunchKernelGGL(hist_kernel, dim3((N_EDGES + 255) / 256), dim3(256), 0, stream,
                     dst, cnt, N_EDGES);
  hipLaunchKernelGGL(scan_kernel, dim3(1), dim3(256), 0, stream, cnt, row_ptr, cursor, N_NODES);
  hipLaunchKernelGGL(scatter_kernel, dim3((N_EDGES + 255) / 256), dim3(256), 0, stream,
                     src, dst, cursor, csr_src, N_EDGES);

  // --- node_feat -> fp16 plane; hidden weights -> transposed fp16 (batched) ---
  int n4 = N_NODES * EMB / 4;
  hipLaunchKernelGGL(convert_f32_f16_kernel, dim3((n4 + 255) / 256), dim3(256), 0, stream,
                     node_feat, Pin, n4);
  hipLaunchKernelGGL(convert_wt_kernel, dim3(HFEAT / 32, HFEAT / 32, 8),
                     dim3(256), 0, stream, Wh, whh, HFEAT, HFEAT);

  // --- GAT layer 1: Pin(768) -> feat P0 -> h1 P1 (2048) ---
  gat_layer(Pin, EMB, W1, wt, al1, ar1, b1, row_ptr, csr_src,
            P0, el, er, e_buf, P1, stream);
  // --- GAT layer 2: P1(2048) -> feat P0 -> h2 P1 (2048) ---
  gat_layer(P1, HDTOT, W2, wt, al2, ar2, b2, row_ptr, csr_src,
            P0, el, er, e_buf, P1, stream);

  // --- h = elu(P1 @ Wfc + bfc) -> P0 (N x 512) --- (R6: <128> tile)
  gemm(P1, Wfc, wt, bfc, P0, N_NODES, HFEAT, HDTOT, 1, false, stream);

  // --- 8 hidden layers: chained gemm<128> (R6: switched from <64>) ---
  _Float16* cur = P0;
  _Float16* nxt = P1;
  for (int i = 0; i < 8; ++i) {
    gemm_raw(cur, whh + (size_t)i * HFEAT * HFEAT, bh + (size_t)i * HFEAT, nxt,
             N_NODES, HFEAT, HFEAT, 1, false, stream);
    _Float16* tmp = cur; cur = nxt; nxt = tmp;
  }
  // after 8 swaps, cur == P0 holds the final h

  // --- fused mean-pool + BN + fc + classifier ---
  hipLaunchKernelGGL(pool_final_kernel, dim3(N_GRAPHS), dim3(512), 0, stream,
                     cur, graph_id, gamma, beta, Whfc, bhfc, Wf, bf, out);
}

// Round 7
// 701.301 us; speedup vs baseline: 1.1192x; 1.1192x over previous
//
#include <hip/hip_runtime.h>
#include <hip/hip_bf16.h>
#include <math.h>

// Problem constants (from reference)
#define N_NODES 10000
#define N_EDGES 80000
#define N_GRAPHS 64
#define NH 4
#define HD 512
#define HDTOT 2048   // NH*HD
#define EMB 768
#define HFEAT 512
#define MAXDEG 512   // LDS softmax-weight capacity per node

typedef _Float16 half8 __attribute__((ext_vector_type(8)));
typedef _Float16 half4 __attribute__((ext_vector_type(4)));
typedef float f32x4 __attribute__((ext_vector_type(4)));

// Async global->LDS, 16B per lane. LDS dest = wave-uniform base + lane*16;
// the GLOBAL SOURCE ADDRESS IS PER-LANE. Lanes fetch their row's K-granules
// in XOR-permuted order (g8 ^ (r&7)), so the DMA lands a swizzled LDS image
// from a PLAIN row-major global plane. With BK=64 (row stride 128 B = all 32
// banks), fragment ds_read_b128s at granule (kk*4+fq)^(m&7) hit 8 bank
// groups x 2 lanes = 2-way aliasing (free). Zero VALU repack.
__device__ __forceinline__ void gload_lds16(const void* g, void* l) {
  __builtin_amdgcn_global_load_lds(
      (const __attribute__((address_space(1))) unsigned int*)g,
      (__attribute__((address_space(3))) unsigned int*)l, 16, 0, 0);
}

// ---------------------------------------------------------------------------
// Plain-fp16 MFMA GEMM: C = act(A @ B + bias), C stored as fp16 plane.
// A: MxK fp16 row-major. BT: NxK fp16 row-major (plain transpose).
// BOTH staged via source-swizzled global_load_lds. BK=64.
// Epilogue: per-wave LDS bounce -> 16B coalesced C stores.
// Tile BM x 128, 256 threads. BM=128: waves 2x2; BM=64: 1x4. K%64==0.
//
// SESSION LEDGER (R0-R6, all refcheck-passed, counters in journal):
//  * This m97-structure kernel: 763 TF eff., MfmaUtil 34.5 — the timed-total
//    winner (703.5/708.3 us, the two best of 7 runs).
//  * R1/R2 coarse counted-vmcnt 256^2: 697 TF at full machine — WORSE
//    (1-phase counted-vmcnt is null per guide m196).
//  * R5 fine-phased 256^2 (4-phase, counted vmcnt): 852 TF per-dispatch,
//    MfmaUtil 36.6 — but only ~-9 us net after M-split overheads; timed
//    totals (738) never confirmed; dropped as unverifiable vs +-25 noise.
//  * R6 two-barrier phase + setprio: null-to-negative (34.7 util).
//  * R3 block-fused hidden8: 78 TF (per-wave L2 B-stream, occ 7%). Dead.
//  * R4 coop grid.sync hidden chain: 1080 us profiled. Dead.
//  * <64> vs <128> for the nine N=512 GEMMs: <64> wins (628 blocks balance;
//    316 <128> blocks imbalance, +2 us/dispatch — R6).
//  * r12 (prev session): do NOT fuse reductions into this epilogue.
// Remaining slack is launch gaps + small-GEMM ramp + softmax L3-gather
// floor; five structural attacks failed with identified causes. This is
// the practical plateau for this op graph.
// ---------------------------------------------------------------------------
template <int BM>
__global__ __launch_bounds__(256) void gemm_f16_kernel(
    const _Float16* __restrict__ A, const _Float16* __restrict__ BT,
    const float* __restrict__ bias, _Float16* __restrict__ C,
    int M, int N, int K, int act) {
  constexpr int WR = (BM == 128) ? 2 : 1;  // wave grid rows
  constexpr int WC = 4 / WR;               // wave grid cols
  constexpr int MI = (BM / WR) / 16;       // m-frags per wave (4)
  constexpr int NI = (128 / WC) / 16;      // n-frags per wave (4 or 2)
  constexpr int NW = NI * 16;              // wave n-width (64 or 32)
  constexpr int CS = NW + 4;               // epilogue scratch row stride
  constexpr int GPR = NW / 8;              // 16B granules per scratch row

  __shared__ _Float16 smem[(BM + 128) * 64];
  _Float16* As = smem;             // BM x 64 (swizzled image)
  _Float16* Bs = smem + BM * 64;   // 128 x 64 (swizzled image)

  const int bn = blockIdx.x * 128, bm = blockIdx.y * BM;
  const int t = threadIdx.x;
  const int lane = t & 63, wave = t >> 6;
  const int wr = wave / WC, wc = wave % WC;
  const int m0 = wr * (BM / WR), n0 = wc * NW;
  const int fr = lane & 15, fq = lane >> 4;

  f32x4 acc[MI][NI];
#pragma unroll
  for (int i = 0; i < MI; ++i)
#pragma unroll
    for (int j = 0; j < NI; ++j) acc[i][j] = (f32x4){0.f, 0.f, 0.f, 0.f};

  for (int k0 = 0; k0 < K; k0 += 64) {
    __syncthreads();  // protect LDS from previous iteration's readers
    // ---- stage A via source-swizzled global_load_lds: BM x 64 ----
#pragma unroll
    for (int it = 0; it < BM / 32; ++it) {
      int gid = it * 256 + t;
      int r = gid >> 3;
      int q = (gid & 7) ^ (r & 7);  // fetch permuted granule
      int grow = bm + r;
      if (grow >= M) grow = M - 1;  // clamp; garbage masked in epilogue
      gload_lds16(A + (size_t)grow * K + k0 + q * 8,
                  &As[(it * 256 + wave * 64) * 8]);
    }
    // ---- stage B via source-swizzled global_load_lds: 128 x 64 ----
#pragma unroll
    for (int it = 0; it < 4; ++it) {
      int gid = it * 256 + t;
      int r = gid >> 3;
      int q = (gid & 7) ^ (r & 7);
      gload_lds16(BT + (size_t)(bn + r) * K + k0 + q * 8,
                  &Bs[(it * 256 + wave * 64) * 8]);
    }
    __syncthreads();

#pragma unroll
    for (int kk = 0; kk < 2; ++kk) {
      half8 af[MI], bf[NI];
#pragma unroll
      for (int mi = 0; mi < MI; ++mi) {
        int m = m0 + mi * 16 + fr;
        af[mi] = *(const half8*)&As[m * 64 + (((kk * 4 + fq) ^ (m & 7))) * 8];
      }
#pragma unroll
      for (int ni = 0; ni < NI; ++ni) {
        int n = n0 + ni * 16 + fr;
        bf[ni] = *(const half8*)&Bs[n * 64 + (((kk * 4 + fq) ^ (n & 7))) * 8];
      }
#pragma unroll
      for (int mi = 0; mi < MI; ++mi)
#pragma unroll
        for (int ni = 0; ni < NI; ++ni)
          acc[mi][ni] = __builtin_amdgcn_mfma_f32_16x16x32_f16(
              af[mi], bf[ni], acc[mi][ni], 0, 0, 0);
    }
  }
  // ---- epilogue: bias+act, per-wave LDS bounce, 16B coalesced stores ----
  __syncthreads();  // all K-loop LDS reads done; staging smem reusable
  _Float16* cs = smem + wave * 16 * CS;  // wave-private scratch (16 x CS)
#pragma unroll
  for (int mi = 0; mi < MI; ++mi) {
#pragma unroll
    for (int ni = 0; ni < NI; ++ni) {
      float bb = bias ? bias[bn + n0 + ni * 16 + fr] : 0.f;
#pragma unroll
      for (int j = 0; j < 4; ++j) {
        float v = acc[mi][ni][j] + bb;
        if (act == 1) v = v > 0.f ? v : expm1f(v);
        cs[(fq * 4 + j) * CS + ni * 16 + fr] = (_Float16)v;
      }
    }
    // wave-local read-back (compiler orders LDS ops via lgkmcnt)
#pragma unroll
    for (int i = 0; i < NW / 32; ++i) {
      int piece = i * 64 + lane;
      int r = piece / GPR, g = piece % GPR;
      int grow = bm + m0 + mi * 16 + r;
      if (grow < M) {
        half8 v = *(const half8*)&cs[r * CS + g * 8];
        *(half8*)&C[(size_t)grow * N + bn + n0 + g * 8] = v;
      }
    }
  }
}

// ---------------------------------------------------------------------------
// Transpose + convert weights: W (KxN fp32) -> WT (NxK fp16), PLAIN layout.
// blockIdx.z batches matrices (stride K*N).
// ---------------------------------------------------------------------------
__global__ __launch_bounds__(256) void convert_wt_kernel(
    const float* __restrict__ W, _Float16* __restrict__ WT, int K, int N) {
  __shared__ float tile[32][33];
  W += (size_t)blockIdx.z * K * N;
  WT += (size_t)blockIdx.z * K * N;
  int k0 = blockIdx.x * 32, n0 = blockIdx.y * 32;
  int t = threadIdx.x;
  int r = t >> 3, c4 = (t & 7) * 4;
  float4 v = *(const float4*)(W + (size_t)(k0 + r) * N + n0 + c4);
  tile[r][c4 + 0] = v.x;
  tile[r][c4 + 1] = v.y;
  tile[r][c4 + 2] = v.z;
  tile[r][c4 + 3] = v.w;
  __syncthreads();
  float x0 = tile[c4 + 0][r], x1 = tile[c4 + 1][r];
  float x2 = tile[c4 + 2][r], x3 = tile[c4 + 3][r];
  size_t o = (size_t)(n0 + r) * K + k0 + c4;
  *(half4*)&WT[o] = (half4){(_Float16)x0, (_Float16)x1, (_Float16)x2, (_Float16)x3};
}

// fp32 -> fp16 plane (for the external node_feat input)
__global__ void convert_f32_f16_kernel(const float* __restrict__ x,
                                       _Float16* __restrict__ y, int n4) {
  int gid = blockIdx.x * blockDim.x + threadIdx.x;
  if (gid >= n4) return;
  float4 v = *(const float4*)(x + gid * 4);
  *(half4*)(y + gid * 4) =
      (half4){(_Float16)v.x, (_Float16)v.y, (_Float16)v.z, (_Float16)v.w};
}

// ---------------------------------------------------------------------------
// CSR build (by dst): histogram -> single-block scan -> scatter.
// Scatter packs src into CSR order (csr_src).
// ---------------------------------------------------------------------------
__global__ void hist_kernel(const int* __restrict__ dst, int* __restrict__ cnt, int E) {
  int gid = blockIdx.x * blockDim.x + threadIdx.x;
  if (gid < E) atomicAdd(&cnt[dst[gid]], 1);
}

__global__ void scan_kernel(const int* __restrict__ cnt, int* __restrict__ row_ptr,
                            int* __restrict__ cursor, int n) {
  __shared__ int part[256];
  int t = threadIdx.x;
  int chunk = (n + 255) / 256;
  int s0 = t * chunk;
  int s1 = min(s0 + chunk, n);
  int sum = 0;
  for (int i = s0; i < s1; ++i) sum += cnt[i];
  part[t] = sum;
  __syncthreads();
  if (t == 0) {
    int acc = 0;
    for (int i = 0; i < 256; ++i) { int v = part[i]; part[i] = acc; acc += v; }
    row_ptr[n] = acc;
  }
  __syncthreads();
  int run = part[t];
  for (int i = s0; i < s1; ++i) {
    row_ptr[i] = run;
    cursor[i] = run;
    run += cnt[i];
  }
}

__global__ void scatter_kernel(const int* __restrict__ src, const int* __restrict__ dst,
                               int* __restrict__ cursor, int* __restrict__ csr_src,
                               int E) {
  int gid = blockIdx.x * blockDim.x + threadIdx.x;
  if (gid < E) {
    int d = dst[gid];
    int pos = atomicAdd(&cursor[d], 1);
    csr_src[pos] = src[gid];
  }
}

// ---------------------------------------------------------------------------
// GAT pieces (feat fp16 plane; edges in CSR order)
// ---------------------------------------------------------------------------
__global__ __launch_bounds__(256) void el_er_kernel(
    const _Float16* __restrict__ feat, const float* __restrict__ al,
    const float* __restrict__ ar, float* __restrict__ el, float* __restrict__ er) {
  int n = blockIdx.x;
  int t = threadIdx.x;
  int h = t >> 6, lane = t & 63;
  half8 f = *(const half8*)(feat + (size_t)n * HDTOT + h * HD + lane * 8);
  const float* ap = al + h * HD + lane * 8;
  const float* rp = ar + h * HD + lane * 8;
  float4 a0 = *(const float4*)ap, a1 = *(const float4*)(ap + 4);
  float4 r0 = *(const float4*)rp, r1 = *(const float4*)(rp + 4);
  float f0 = (float)f[0], f1 = (float)f[1], f2 = (float)f[2], f3 = (float)f[3];
  float f4 = (float)f[4], f5 = (float)f[5], f6 = (float)f[6], f7 = (float)f[7];
  float sl = f0 * a0.x + f1 * a0.y + f2 * a0.z + f3 * a0.w +
             f4 * a1.x + f5 * a1.y + f6 * a1.z + f7 * a1.w;
  float sr = f0 * r0.x + f1 * r0.y + f2 * r0.z + f3 * r0.w +
             f4 * r1.x + f5 * r1.y + f6 * r1.z + f7 * r1.w;
  for (int off = 32; off; off >>= 1) {
    sl += __shfl_down(sl, off);
    sr += __shfl_down(sr, off);
  }
  if (lane == 0) {
    el[n * NH + h] = sl;
    er[n * NH + h] = sr;
  }
}

// ---------------------------------------------------------------------------
// FUSED per-node edge-softmax + aggregate.
// Phase 1 (threads as 4 heads x 64 lanes): leaky-relu logits over the CSR
// range -> max -> exp -> sum -> normalized weights into LDS wl[h][q]
// (register path for deg<=64; global e_buf fallback for deg>MAXDEG).
// Phase 2 (threads as 256 x 8-col granules): out[n,:] = sum_p a[p]*feat[src]
// + bias, weights read from LDS (64-lane broadcast, free).
// ---------------------------------------------------------------------------
__global__ __launch_bounds__(256) void softmax_aggregate_kernel(
    const _Float16* __restrict__ feat, const float* __restrict__ el,
    const float* __restrict__ er, const int* __restrict__ row_ptr,
    const int* __restrict__ csr_src, float* __restrict__ e_buf,
    const float* __restrict__ bias, _Float16* __restrict__ out) {
  __shared__ float wl[NH][MAXDEG];
  int n = blockIdx.x;
  int t = threadIdx.x;
  int h = t >> 6, lane = t & 63;
  int s = row_ptr[n], epos = row_ptr[n + 1];
  int deg = epos - s;
  bool lds_w = (deg <= MAXDEG);

  // ---- phase 1: softmax weights ----
  if (deg > 0) {
    float ern = er[n * NH + h];
    if (deg <= 64) {
      int p = s + lane;
      bool on = lane < deg;
      float logit = 0.f;
      float m = -INFINITY;
      if (on) {
        float v = el[csr_src[p] * NH + h] + ern;
        logit = v >= 0.f ? v : 0.2f * v;
        m = logit;
      }
#pragma unroll
      for (int off = 32; off; off >>= 1) m = fmaxf(m, __shfl_xor(m, off));
      float ex = on ? expf(logit - m) : 0.f;
      float sum = ex;
#pragma unroll
      for (int off = 32; off; off >>= 1) sum += __shfl_xor(sum, off);
      float inv = 1.f / sum;
      if (on) wl[h][lane] = ex * inv;
    } else if (lds_w) {
      float m = -INFINITY;
      for (int p = s + lane; p < epos; p += 64) {
        float v = el[csr_src[p] * NH + h] + ern;
        v = v >= 0.f ? v : 0.2f * v;
        wl[h][p - s] = v;
        m = fmaxf(m, v);
      }
      for (int off = 32; off; off >>= 1) m = fmaxf(m, __shfl_xor(m, off));
      float sum = 0.f;
      for (int p = s + lane; p < epos; p += 64) {
        float ex = expf(wl[h][p - s] - m);
        wl[h][p - s] = ex;
        sum += ex;
      }
      for (int off = 32; off; off >>= 1) sum += __shfl_xor(sum, off);
      float inv = 1.f / sum;
      for (int p = s + lane; p < epos; p += 64) wl[h][p - s] *= inv;
    } else {
      // rare fallback: weights via global scratch
      float m = -INFINITY;
      for (int p = s + lane; p < epos; p += 64) {
        float v = el[csr_src[p] * NH + h] + ern;
        v = v >= 0.f ? v : 0.2f * v;
        e_buf[p * NH + h] = v;
        m = fmaxf(m, v);
      }
      for (int off = 32; off; off >>= 1) m = fmaxf(m, __shfl_xor(m, off));
      float sum = 0.f;
      for (int p = s + lane; p < epos; p += 64) {
        float ex = expf(e_buf[p * NH + h] - m);
        e_buf[p * NH + h] = ex;
        sum += ex;
      }
      for (int off = 32; off; off >>= 1) sum += __shfl_xor(sum, off);
      float inv = 1.f / sum;
      for (int p = s + lane; p < epos; p += 64) e_buf[p * NH + h] *= inv;
    }
  }
  __syncthreads();

  // ---- phase 2: weighted aggregation (4-deep unroll for MLP) ----
  int base = t * 8;
  float acc[8] = {0.f, 0.f, 0.f, 0.f, 0.f, 0.f, 0.f, 0.f};
  int p = s;
  for (; p + 4 <= epos; p += 4) {
    int q = p - s;
    int sn0 = csr_src[p + 0], sn1 = csr_src[p + 1];
    int sn2 = csr_src[p + 2], sn3 = csr_src[p + 3];
    float a0 = lds_w ? wl[h][q + 0] : e_buf[(p + 0) * NH + h];
    float a1 = lds_w ? wl[h][q + 1] : e_buf[(p + 1) * NH + h];
    float a2 = lds_w ? wl[h][q + 2] : e_buf[(p + 2) * NH + h];
    float a3 = lds_w ? wl[h][q + 3] : e_buf[(p + 3) * NH + h];
    half8 f0 = *(const half8*)(feat + (size_t)sn0 * HDTOT + base);
    half8 f1 = *(const half8*)(feat + (size_t)sn1 * HDTOT + base);
    half8 f2 = *(const half8*)(feat + (size_t)sn2 * HDTOT + base);
    half8 f3 = *(const half8*)(feat + (size_t)sn3 * HDTOT + base);
#pragma unroll
    for (int i = 0; i < 8; ++i)
      acc[i] += a0 * (float)f0[i] + a1 * (float)f1[i] +
                a2 * (float)f2[i] + a3 * (float)f3[i];
  }
  for (; p < epos; ++p) {
    int sn = csr_src[p];
    float a = lds_w ? wl[h][p - s] : e_buf[p * NH + h];
    half8 f = *(const half8*)(feat + (size_t)sn * HDTOT + base);
#pragma unroll
    for (int i = 0; i < 8; ++i) acc[i] += a * (float)f[i];
  }
  float4 b0 = *(const float4*)(bias + base);
  float4 b1 = *(const float4*)(bias + base + 4);
  half8 o;
  o[0] = (_Float16)(acc[0] + b0.x); o[1] = (_Float16)(acc[1] + b0.y);
  o[2] = (_Float16)(acc[2] + b0.z); o[3] = (_Float16)(acc[3] + b0.w);
  o[4] = (_Float16)(acc[4] + b1.x); o[5] = (_Float16)(acc[5] + b1.y);
  o[6] = (_Float16)(acc[6] + b1.z); o[7] = (_Float16)(acc[7] + b1.w);
  *(half8*)(out + (size_t)n * HDTOT + base) = o;
}

// ---------------------------------------------------------------------------
// FUSED pool + BN + Whfc matvec + classifier. One block per graph.
// graph_id sorted -> segmented mean; identical math to the reference.
// ---------------------------------------------------------------------------
__global__ __launch_bounds__(512) void pool_final_kernel(
    const _Float16* __restrict__ hfeat, const int* __restrict__ graph_id,
    const float* __restrict__ gamma, const float* __restrict__ beta,
    const float* __restrict__ Whfc, const float* __restrict__ bhfc,
    const float* __restrict__ Wf, const float* __restrict__ bf,
    float* __restrict__ out) {
  __shared__ float sh[HFEAT];
  __shared__ float st[HFEAT];
  __shared__ float r0[8], r1[8];
  __shared__ int s_lo, s_hi;
  int g = blockIdx.x, t = threadIdx.x;
  if (t == 0) {
    int lo = 0, hi = N_NODES;
    while (lo < hi) { int m = (lo + hi) >> 1; if (graph_id[m] < g) lo = m + 1; else hi = m; }
    s_lo = lo;
    int lo2 = lo, hi2 = N_NODES;
    while (lo2 < hi2) { int m = (lo2 + hi2) >> 1; if (graph_id[m] < g + 1) lo2 = m + 1; else hi2 = m; }
    s_hi = lo2;
  }
  __syncthreads();
  int lo = s_lo, hi = s_hi;
  int col = t;  // 512 threads = HFEAT cols
  float acc = 0.f;
  for (int n = lo; n < hi; ++n) acc += (float)hfeat[(size_t)n * HFEAT + col];
  float invc = 1.f / fmaxf((float)(hi - lo), 1.f);
  float bnscale = rsqrtf(1.f + 1e-5f);
  sh[col] = acc * invc * bnscale * gamma[col] + beta[col];
  __syncthreads();
  float a2 = bhfc[col];
  for (int k = 0; k < HFEAT; ++k) a2 += sh[k] * Whfc[k * HFEAT + col];
  st[col] = a2 > 0.f ? a2 : expm1f(a2);
  __syncthreads();
  float p0 = st[col] * Wf[col * 2 + 0];
  float p1 = st[col] * Wf[col * 2 + 1];
  for (int off = 32; off; off >>= 1) {
    p0 += __shfl_down(p0, off);
    p1 += __shfl_down(p1, off);
  }
  int w = t >> 6;
  if ((t & 63) == 0) { r0[w] = p0; r1[w] = p1; }
  __syncthreads();
  if (t == 0) {
    float q0 = bf[0], q1 = bf[1];
#pragma unroll
    for (int i = 0; i < 8; ++i) { q0 += r0[i]; q1 += r1[i]; }
    out[g * 2 + 0] = q0;
    out[g * 2 + 1] = q1;
  }
}

// ---------------------------------------------------------------------------
// Host-side launch
// ---------------------------------------------------------------------------
static void gemm_raw(const _Float16* A, const _Float16* wt, const float* bias,
                     _Float16* C, int M, int N, int K, int act,
                     bool small_m_tile, hipStream_t stream) {
  if (small_m_tile) {
    dim3 grid(N / 128, (M + 63) / 64);
    hipLaunchKernelGGL(gemm_f16_kernel<64>, grid, dim3(256), 0, stream,
                       A, wt, bias, C, M, N, K, act);
  } else {
    dim3 grid(N / 128, (M + 127) / 128);
    hipLaunchKernelGGL(gemm_f16_kernel<128>, grid, dim3(256), 0, stream,
                       A, wt, bias, C, M, N, K, act);
  }
}

static void gemm(const _Float16* A, const float* W, _Float16* wt,
                 const float* bias, _Float16* C, int M, int N, int K, int act,
                 bool small_m_tile, hipStream_t stream) {
  hipLaunchKernelGGL(convert_wt_kernel, dim3(K / 32, N / 32, 1), dim3(256),
                     0, stream, W, wt, K, N);
  gemm_raw(A, wt, bias, C, M, N, K, act, small_m_tile, stream);
}

static void gat_layer(const _Float16* h_in, int K_in, const float* W, _Float16* wt,
                      const float* al, const float* ar, const float* b,
                      const int* row_ptr, const int* csr_src,
                      _Float16* featbuf, float* el, float* er,
                      float* e_buf, _Float16* out, hipStream_t stream) {
  gemm(h_in, W, wt, nullptr, featbuf, N_NODES, HDTOT, K_in, 0, false, stream);
  hipLaunchKernelGGL(el_er_kernel, dim3(N_NODES), dim3(256), 0, stream, featbuf, al, ar, el, er);
  hipLaunchKernelGGL(softmax_aggregate_kernel, dim3(N_NODES), dim3(256), 0, stream,
                     featbuf, el, er, row_ptr, csr_src, e_buf, b, out);
}

extern "C" void kernel_launch(void* const* d_in, const int* in_sizes, int n_in,
                              void* d_out, int out_size, void* d_ws, size_t ws_size,
                              hipStream_t stream) {
  const float* node_feat = (const float*)d_in[0];
  const float* W1 = (const float*)d_in[2];
  const float* al1 = (const float*)d_in[3];
  const float* ar1 = (const float*)d_in[4];
  const float* b1 = (const float*)d_in[5];
  const float* W2 = (const float*)d_in[6];
  const float* al2 = (const float*)d_in[7];
  const float* ar2 = (const float*)d_in[8];
  const float* b2 = (const float*)d_in[9];
  const float* Wfc = (const float*)d_in[10];
  const float* bfc = (const float*)d_in[11];
  const float* Wh = (const float*)d_in[14];
  const float* bh = (const float*)d_in[15];
  const float* gamma = (const float*)d_in[16];
  const float* beta = (const float*)d_in[17];
  const float* Whfc = (const float*)d_in[18];
  const float* bhfc = (const float*)d_in[19];
  const float* Wf = (const float*)d_in[20];
  const float* bf = (const float*)d_in[21];
  const int* src = (const int*)d_in[22];
  const int* dst = (const int*)d_in[23];
  const int* graph_id = (const int*)d_in[24];
  float* out = (float*)d_out;

  // Workspace carve-up
  _Float16* P0 = (_Float16*)d_ws;                 // 10000*2048 fp16
  _Float16* P1 = P0 + (size_t)N_NODES * HDTOT;    // 10000*2048 fp16
  _Float16* Pin = P1 + (size_t)N_NODES * HDTOT;   // 10000*768 fp16
  _Float16* wt = Pin + (size_t)N_NODES * EMB;     // 2048*2048 fp16 (shared)
  _Float16* whh = wt + (size_t)2048 * 2048;       // 8*512*512 fp16 (hidden)
  float* el = (float*)(whh + (size_t)8 * HFEAT * HFEAT);
  float* er = el + N_NODES * NH;
  float* e_buf = er + N_NODES * NH;       // N_EDGES*NH (fallback scratch)
  int* cnt = (int*)(e_buf + (size_t)N_EDGES * NH);
  int* row_ptr = cnt + N_NODES;           // N_NODES+1
  int* cursor = row_ptr + N_NODES + 1;
  int* csr_src = cursor + N_NODES;        // N_EDGES

  // --- CSR build (by dst), once per launch ---
  hipMemsetAsync(cnt, 0, N_NODES * sizeof(int), stream);
  hipLaunchKernelGGL(hist_kernel, dim3((N_EDGES + 255) / 256), dim3(256), 0, stream,
                     dst, cnt, N_EDGES);
  hipLaunchKernelGGL(scan_kernel, dim3(1), dim3(256), 0, stream, cnt, row_ptr, cursor, N_NODES);
  hipLaunchKernelGGL(scatter_kernel, dim3((N_EDGES + 255) / 256), dim3(256), 0, stream,
                     src, dst, cursor, csr_src, N_EDGES);

  // --- node_feat -> fp16 plane; hidden weights -> transposed fp16 (batched) ---
  int n4 = N_NODES * EMB / 4;
  hipLaunchKernelGGL(convert_f32_f16_kernel, dim3((n4 + 255) / 256), dim3(256), 0, stream,
                     node_feat, Pin, n4);
  hipLaunchKernelGGL(convert_wt_kernel, dim3(HFEAT / 32, HFEAT / 32, 8),
                     dim3(256), 0, stream, Wh, whh, HFEAT, HFEAT);

  // --- GAT layer 1: Pin(768) -> feat P0 -> h1 P1 (2048) ---
  gat_layer(Pin, EMB, W1, wt, al1, ar1, b1, row_ptr, csr_src,
            P0, el, er, e_buf, P1, stream);
  // --- GAT layer 2: P1(2048) -> feat P0 -> h2 P1 (2048) ---
  gat_layer(P1, HDTOT, W2, wt, al2, ar2, b2, row_ptr, csr_src,
            P0, el, er, e_buf, P1, stream);

  // --- h = elu(P1 @ Wfc + bfc) -> P0 (N x 512) ---
  gemm(P1, Wfc, wt, bfc, P0, N_NODES, HFEAT, HDTOT, 1, true, stream);

  // --- 8 hidden layers: chained gemm<64>, weights pre-converted ---
  _Float16* cur = P0;
  _Float16* nxt = P1;
  for (int i = 0; i < 8; ++i) {
    gemm_raw(cur, whh + (size_t)i * HFEAT * HFEAT, bh + (size_t)i * HFEAT, nxt,
             N_NODES, HFEAT, HFEAT, 1, true, stream);
    _Float16* tmp = cur; cur = nxt; nxt = tmp;
  }
  // after 8 swaps, cur == P0 holds the final h

  // --- fused mean-pool + BN + fc + classifier ---
  hipLaunchKernelGGL(pool_final_kernel, dim3(N_GRAPHS), dim3(512), 0, stream,
                     cur, graph_id, gamma, beta, Whfc, bhfc, Wf, bf, out);
}